// Round 11
// baseline (299.275 us; speedup 1.0000x reference)
//
#include <hip/hip_runtime.h>

#define N_NODES 50000
#define IN_SIZE 512
#define HID 128
#define OUT 64
#define NB 256                 // edge-partition blocks (hist/scatter)
#define SHIFT 7                // bucket = dst >> 7  (128 nodes per bucket)
#define NBUCK 391              // ceil(50000/128)

typedef _Float16 f16x8 __attribute__((ext_vector_type(8)));
typedef _Float16 f16x4 __attribute__((ext_vector_type(4)));
typedef float    f32x4 __attribute__((ext_vector_type(4)));

// ---------- inline int64-vs-int32 layout detection (per block, no extra dispatch) ----------
__device__ __forceinline__ bool detect_w(const int* p, int t, int* sh) {
    if (t < 64) {
        unsigned long long m = __ballot(p[2 * t + 1] == 0);
        if (t == 0) *sh = (m == ~0ull) ? 1 : 0;
    }
    __syncthreads();
    return *sh != 0;
}

__device__ __forceinline__ int load_idx(const void* p, int e, bool w) {
    return w ? (int)((const long long*)p)[e] : ((const int*)p)[e];
}

// ---------- pass 0: zero the global out-degree counters (workspace is re-poisoned each iter) ----------
__global__ __launch_bounds__(256) void k_zero(unsigned int* __restrict__ outdeg) {
    int i = blockIdx.x * 256 + threadIdx.x;
    if (i < N_NODES) outdeg[i] = 0u;
}

// ---------- pass 1: coarse dst histogram (1.6KB LDS) + GLOBAL-atomic out-degree + weight transpose ----------
// R10 post-mortem: the 50KB packed-u8 src-histogram capped this 12.8MB-streaming kernel at ~3
// blocks/CU and cost a 12.8MB spart write + 12.8MB re-read in k_fine. Out-degree now goes to a
// global 200KB counter array via fire-and-forget atomicAdd (800K adds / 50K counters ~= 16 per
// counter -> negligible contention, no wait on the result). LDS drops to 1.6KB -> high occupancy.
__global__ __launch_bounds__(256) void k_hist_wt(const void* __restrict__ srcp,
                                                 const void* __restrict__ dstp,
                                                 int* __restrict__ hist,
                                                 unsigned int* __restrict__ outdeg,
                                                 int E, int EPB,
                                                 const float* __restrict__ W1, _Float16* __restrict__ W1T,
                                                 const float* __restrict__ W2, _Float16* __restrict__ W2T) {
    const int t = threadIdx.x, b = blockIdx.x;
    if (b >= NB) {   // weight transpose tail blocks
        int i = (b - NB) * 256 + t;
        if (i < IN_SIZE * HID) {
            int k = i >> 7, n = i & (HID - 1);
            W1T[(size_t)n * IN_SIZE + k] = (_Float16)W1[i];
        } else {
            int j = i - IN_SIZE * HID;
            if (j < HID * OUT) {
                int k = j >> 6, n = j & (OUT - 1);
                W2T[(size_t)n * HID + k] = (_Float16)W2[j];
            }
        }
        return;
    }
    __shared__ int dbins[NBUCK];             // 1.6 KB
    __shared__ int shw;
    for (int i = t; i < NBUCK; i += 256) dbins[i] = 0;
    bool w = detect_w((const int*)dstp, t, &shw);
    __syncthreads();
    int eend = min(E, (b + 1) * EPB);
    for (int e = b * EPB + t; e < eend; e += 256) {
        int s = load_idx(srcp, e, w);
        int d = load_idx(dstp, e, w);
        atomicAdd(&dbins[d >> SHIFT], 1);
        atomicAdd(&outdeg[s], 1u);           // global, fire-and-forget
    }
    __syncthreads();
    for (int i = t; i < NBUCK; i += 256) hist[i * NB + b] = dbins[i];
}

// ---------- pass 2: scan hist (bucket-major) ----------
__global__ __launch_bounds__(256) void k_scanA(int* __restrict__ hist, int* __restrict__ bsum) {
    __shared__ int s[256];
    const int t = threadIdx.x, g = blockIdx.x;
    int v = hist[g * NB + t];
    s[t] = v;
    __syncthreads();
    for (int off = 1; off < 256; off <<= 1) {
        int u = (t >= off) ? s[t - off] : 0;
        __syncthreads();
        s[t] += u;
        __syncthreads();
    }
    hist[g * NB + t] = s[t] - v;
    if (t == 255) bsum[g] = s[255];
}

__global__ __launch_bounds__(512) void k_scanB(const int* __restrict__ bsum, int* __restrict__ bb) {
    __shared__ int s[512];
    const int t = threadIdx.x;
    int v = (t < NBUCK) ? bsum[t] : 0;
    s[t] = v;
    __syncthreads();
    for (int off = 1; off < 512; off <<= 1) {
        int u = (t >= off) ? s[t - off] : 0;
        __syncthreads();
        s[t] += u;
        __syncthreads();
    }
    if (t <= NBUCK) bb[t] = s[t] - v;     // bb[NBUCK] = total = E
}

// ---------- pass 3: coarse scatter, packed (src | dl<<16) ----------
__global__ __launch_bounds__(256) void k_cscatter(const void* __restrict__ srcp,
                                                  const void* __restrict__ dstp,
                                                  const int* __restrict__ hist,
                                                  const int* __restrict__ bb,
                                                  unsigned int* __restrict__ tmp,
                                                  int E, int EPB) {
    __shared__ int cur[NBUCK];
    __shared__ int shw;
    const int t = threadIdx.x, b = blockIdx.x;
    for (int i = t; i < NBUCK; i += 256) cur[i] = hist[i * NB + b] + bb[i];
    bool w = detect_w((const int*)dstp, t, &shw);
    __syncthreads();
    int eend = min(E, (b + 1) * EPB);
    for (int e = b * EPB + t; e < eend; e += 256) {
        int s = load_idx(srcp, e, w);
        int d = load_idx(dstp, e, w);
        int pos = atomicAdd(&cur[d >> SHIFT], 1);
        tmp[pos] = (unsigned int)s | ((unsigned int)(d & 127) << 16);
    }
}

// ---------- pass 4: fine count + scan + scatter; writes rp, innorm, onorm (onorm from global outdeg) ----------
__global__ __launch_bounds__(256) void k_fine(const unsigned int* __restrict__ tmp,
                                              const int* __restrict__ bb,
                                              const unsigned int* __restrict__ outdeg,
                                              int* __restrict__ rp,
                                              int* __restrict__ esrc,
                                              float* __restrict__ innorm,
                                              float* __restrict__ onorm) {
    __shared__ int fcnt[128];
    __shared__ int sc[128];
    __shared__ int fcur[128];
    const int t = threadIdx.x, u = blockIdx.x;
    const int e0 = bb[u], e1 = bb[u + 1];
    if (t < 128) fcnt[t] = 0;
    __syncthreads();
    for (int e = e0 + t; e < e1; e += 256)
        atomicAdd(&fcnt[tmp[e] >> 16], 1);
    __syncthreads();   // covers fcnt atomics
    if (t < 128) sc[t] = fcnt[t];
    __syncthreads();
    for (int off = 1; off < 128; off <<= 1) {
        int v = (t < 128 && t >= off) ? sc[t - off] : 0;
        __syncthreads();
        if (t < 128) sc[t] += v;
        __syncthreads();
    }
    if (t < 128) {
        int base = e0 + sc[t] - fcnt[t];
        fcur[t] = base;
        int node = u * 128 + t;
        if (node < N_NODES) {
            rp[node] = base;
            int c = fcnt[t]; if (c < 1) c = 1;
            innorm[node] = 1.0f / sqrtf((float)c);
            unsigned int od = outdeg[node]; if (od < 1u) od = 1u;
            onorm[node] = 1.0f / sqrtf((float)od);
        }
    }
    if (u == NBUCK - 1 && t == 0) rp[N_NODES] = e1;
    __syncthreads();
    for (int e = e0 + t; e < e1; e += 256) {
        unsigned int p = tmp[e];
        int pos = atomicAdd(&fcur[p >> 16], 1);
        esrc[pos] = (int)(p & 0xFFFFu);
    }
}

// ---------- GEMM1 (MFMA fp16, col-split for TLP, R10 version): X1 = fp16( onorm * (feat @ W1) ) ----------
#define LDA 44  // 32 + 12 halfs pad (conflict-free, verified R3)
__global__ __launch_bounds__(256) void k_gemm1_mfma(const float* __restrict__ A,
                                                    const _Float16* __restrict__ BT,
                                                    const float* __restrict__ onorm,
                                                    _Float16* __restrict__ X) {
    __shared__ _Float16 As[2][64 * LDA];
    __shared__ _Float16 Bs[2][64 * LDA];
    const int tid  = threadIdx.x;
    const int wave = tid >> 6, lane = tid & 63;
    const int lm = lane & 15, lq = lane >> 4;
    const int row0 = (blockIdx.x >> 1) * 64;
    const int ch   = (blockIdx.x & 1) * 64;   // output col offset (HID half)

    const int ar = tid >> 2, aq = tid & 3;    // A: row 0..63, 8-float quarter 0..3
    int arow = row0 + ar; if (arow >= N_NODES) arow = N_NODES - 1;
    const float* aptr = A + (size_t)arow * IN_SIZE + aq * 8;
    const int bn = tid >> 2, bq = tid & 3;    // B: local row 0..63, 8-half quarter 0..3
    const _Float16* bptr = BT + (size_t)(ch + bn) * IN_SIZE + bq * 8;

    f32x4 acc[4];
#pragma unroll
    for (int nt = 0; nt < 4; ++nt) acc[nt] = (f32x4){0.f, 0.f, 0.f, 0.f};

    // prologue: stage tile 0 into buffer 0
    {
        float4 a0 = *(const float4*)(aptr);
        float4 a1 = *(const float4*)(aptr + 4);
        f16x8  b0 = *(const f16x8*)(bptr);
        f16x8 ap = {(_Float16)a0.x, (_Float16)a0.y, (_Float16)a0.z, (_Float16)a0.w,
                    (_Float16)a1.x, (_Float16)a1.y, (_Float16)a1.z, (_Float16)a1.w};
        *(f16x8*)&As[0][ar * LDA + aq * 8] = ap;
        *(f16x8*)&Bs[0][bn * LDA + bq * 8] = b0;
    }
    __syncthreads();

#pragma unroll
    for (int kt = 0; kt < IN_SIZE / 32; ++kt) {
        const int k0 = kt * 32;
        const int cur = kt & 1;
        // issue next tile's global loads (in flight during the MFMAs below)
        float4 na0, na1; f16x8 nb0;
        const bool more = (k0 + 32) < IN_SIZE;
        if (more) {
            na0 = *(const float4*)(aptr + k0 + 32);
            na1 = *(const float4*)(aptr + k0 + 36);
            nb0 = *(const f16x8*)(bptr + k0 + 32);
        }
        // compute current buffer: 1 A-frag x 4 B-frags
        f16x8 af = *(const f16x8*)&As[cur][(wave * 16 + lm) * LDA + lq * 8];
#pragma unroll
        for (int nt = 0; nt < 4; ++nt) {
            f16x8 bf = *(const f16x8*)&Bs[cur][(nt * 16 + lm) * LDA + lq * 8];
            acc[nt] = __builtin_amdgcn_mfma_f32_16x16x32_f16(af, bf, acc[nt], 0, 0, 0);
        }
        // write-late into the other buffer, single barrier
        if (more) {
            f16x8 ap = {(_Float16)na0.x, (_Float16)na0.y, (_Float16)na0.z, (_Float16)na0.w,
                        (_Float16)na1.x, (_Float16)na1.y, (_Float16)na1.z, (_Float16)na1.w};
            *(f16x8*)&As[cur ^ 1][ar * LDA + aq * 8] = ap;
            *(f16x8*)&Bs[cur ^ 1][bn * LDA + bq * 8] = nb0;
            __syncthreads();
        }
    }
#pragma unroll
    for (int i = 0; i < 4; ++i) {
        int row = row0 + wave * 16 + lq * 4 + i;
        if (row < N_NODES) {
            float on = onorm[row];
            _Float16* o = X + (size_t)row * HID + ch + lm;
#pragma unroll
            for (int nt = 0; nt < 4; ++nt)
                o[nt * 16] = (_Float16)(acc[nt][i] * on);
        }
    }
}

// ---------- agg1 + fused GEMM2: X2 = fp16( H @ W2 ),  H = relu(gather(X1)*innorm + b1)*onorm ----------
// 16 lanes/node, 8 cols/lane (16B loads), 8-edge unroll (R6-verified pattern): 8 outstanding
// 16B gathers per lane against the L3-resident X1 table.
#define LDH 136  // 128 + 8 halfs pad
__global__ __launch_bounds__(256) void k_agg1_fused(const _Float16* __restrict__ X, const int* __restrict__ rp,
                                                    const int* __restrict__ esrc, const float* __restrict__ innorm,
                                                    const float* __restrict__ onorm, const float* __restrict__ b1,
                                                    const _Float16* __restrict__ W2T, _Float16* __restrict__ X2) {
    __shared__ _Float16 Hs[16 * LDH];
    const int t = threadIdx.x;
    const int ln = t >> 4;           // local node 0..15
    const int c  = (t & 15) << 3;    // col 0..120 step 8
    const int n  = blockIdx.x * 16 + ln;   // grid exact: 3125*16 == 50000
    const int e0 = rp[n], e1 = rp[n + 1];
    float a[8] = {0.f, 0.f, 0.f, 0.f, 0.f, 0.f, 0.f, 0.f};
    int e = e0;
    for (; e + 7 < e1; e += 8) {
        f16x8 v0 = *(const f16x8*)&X[(size_t)esrc[e]     * HID + c];
        f16x8 v1 = *(const f16x8*)&X[(size_t)esrc[e + 1] * HID + c];
        f16x8 v2 = *(const f16x8*)&X[(size_t)esrc[e + 2] * HID + c];
        f16x8 v3 = *(const f16x8*)&X[(size_t)esrc[e + 3] * HID + c];
        f16x8 v4 = *(const f16x8*)&X[(size_t)esrc[e + 4] * HID + c];
        f16x8 v5 = *(const f16x8*)&X[(size_t)esrc[e + 5] * HID + c];
        f16x8 v6 = *(const f16x8*)&X[(size_t)esrc[e + 6] * HID + c];
        f16x8 v7 = *(const f16x8*)&X[(size_t)esrc[e + 7] * HID + c];
#pragma unroll
        for (int j = 0; j < 8; ++j)
            a[j] += (((float)v0[j] + (float)v1[j]) + ((float)v2[j] + (float)v3[j])) +
                    (((float)v4[j] + (float)v5[j]) + ((float)v6[j] + (float)v7[j]));
    }
    for (; e < e1; ++e) {
        f16x8 v = *(const f16x8*)&X[(size_t)esrc[e] * HID + c];
#pragma unroll
        for (int j = 0; j < 8; ++j) a[j] += (float)v[j];
    }
    const float inn = innorm[n], on = onorm[n];
    float4 bA = *(const float4*)&b1[c];
    float4 bB = *(const float4*)&b1[c + 4];
    const float bv[8] = {bA.x, bA.y, bA.z, bA.w, bB.x, bB.y, bB.z, bB.w};
    f16x8 h;
#pragma unroll
    for (int j = 0; j < 8; ++j)
        h[j] = (_Float16)(fmaxf(a[j] * inn + bv[j], 0.f) * on);
    *(f16x8*)&Hs[ln * LDH + c] = h;
    __syncthreads();

    // fused 16x128 @ 128x64: wave w owns output cols w*16..w*16+15 over the block's 16 nodes
    const int wave = t >> 6, lane = t & 63;
    const int lm = lane & 15, lq = lane >> 4;
    f32x4 acc = (f32x4){0.f, 0.f, 0.f, 0.f};
#pragma unroll
    for (int k0 = 0; k0 < HID; k0 += 32) {
        f16x8 af = *(const f16x8*)&Hs[lm * LDH + k0 + lq * 8];
        f16x8 bf = *(const f16x8*)&W2T[(size_t)(wave * 16 + lm) * HID + k0 + lq * 8];
        acc = __builtin_amdgcn_mfma_f32_16x16x32_f16(af, bf, acc, 0, 0, 0);
    }
    const int n0 = blockIdx.x * 16;
#pragma unroll
    for (int i = 0; i < 4; ++i) {
        int row = n0 + lq * 4 + i;
        X2[(size_t)row * OUT + wave * 16 + lm] = (_Float16)acc[i];
    }
}

// ---------- agg2: out = gather-sum(X2)*in_norm + b2  (fp32 out), 8-edge unroll ----------
__global__ __launch_bounds__(256) void k_agg2(const _Float16* __restrict__ X2, const int* __restrict__ rp,
                                              const int* __restrict__ esrc, const float* __restrict__ innorm,
                                              const float* __restrict__ b2, float* __restrict__ out) {
    const int n = blockIdx.x * 32 + (threadIdx.x >> 3);
    const int c = (threadIdx.x & 7) << 3;
    if (n >= N_NODES) return;
    const int e0 = rp[n], e1 = rp[n + 1];
    float a[8] = {0.f, 0.f, 0.f, 0.f, 0.f, 0.f, 0.f, 0.f};
    int e = e0;
    for (; e + 7 < e1; e += 8) {
        f16x8 v0 = *(const f16x8*)&X2[(size_t)esrc[e]     * OUT + c];
        f16x8 v1 = *(const f16x8*)&X2[(size_t)esrc[e + 1] * OUT + c];
        f16x8 v2 = *(const f16x8*)&X2[(size_t)esrc[e + 2] * OUT + c];
        f16x8 v3 = *(const f16x8*)&X2[(size_t)esrc[e + 3] * OUT + c];
        f16x8 v4 = *(const f16x8*)&X2[(size_t)esrc[e + 4] * OUT + c];
        f16x8 v5 = *(const f16x8*)&X2[(size_t)esrc[e + 5] * OUT + c];
        f16x8 v6 = *(const f16x8*)&X2[(size_t)esrc[e + 6] * OUT + c];
        f16x8 v7 = *(const f16x8*)&X2[(size_t)esrc[e + 7] * OUT + c];
#pragma unroll
        for (int j = 0; j < 8; ++j)
            a[j] += (((float)v0[j] + (float)v1[j]) + ((float)v2[j] + (float)v3[j])) +
                    (((float)v4[j] + (float)v5[j]) + ((float)v6[j] + (float)v7[j]));
    }
    for (; e < e1; ++e) {
        f16x8 v = *(const f16x8*)&X2[(size_t)esrc[e] * OUT + c];
#pragma unroll
        for (int j = 0; j < 8; ++j) a[j] += (float)v[j];
    }
    const float inn = innorm[n];
    float4 bA = *(const float4*)&b2[c];
    float4 bB = *(const float4*)&b2[c + 4];
    float* o = out + (size_t)n * OUT + c;
    *(float4*)o       = make_float4(a[0] * inn + bA.x, a[1] * inn + bA.y,
                                    a[2] * inn + bA.z, a[3] * inn + bA.w);
    *(float4*)(o + 4) = make_float4(a[4] * inn + bB.x, a[5] * inn + bB.y,
                                    a[6] * inn + bB.z, a[7] * inn + bB.w);
}

extern "C" void kernel_launch(void* const* d_in, const int* in_sizes, int n_in,
                              void* d_out, int out_size, void* d_ws, size_t ws_size,
                              hipStream_t stream) {
    const float* feat = (const float*)d_in[0];
    const float* W1   = (const float*)d_in[1];
    const float* b1   = (const float*)d_in[2];
    const float* W2   = (const float*)d_in[3];
    const float* b2   = (const float*)d_in[4];
    const void*  srcp = (const void*)d_in[5];
    const void*  dstp = (const void*)d_in[6];
    const int    E    = in_sizes[5];
    float* out = (float*)d_out;

    char* w = (char*)d_ws;
    size_t off = 0;
    auto alloc = [&](size_t bytes) -> void* {
        off = (off + 255) & ~(size_t)255;
        void* p = w + off;
        off += bytes;
        return p;
    };
    int*   hist    = (int*)alloc((size_t)NBUCK * NB * 4);
    int*   bsum    = (int*)alloc((size_t)NBUCK * 4);
    int*   bb      = (int*)alloc((size_t)(NBUCK + 1) * 4);
    int*   rp      = (int*)alloc((size_t)(N_NODES + 1) * 4);
    unsigned int* outdeg = (unsigned int*)alloc((size_t)N_NODES * 4);
    unsigned int* tmp   = (unsigned int*)alloc((size_t)E * 4);
    int*   esrc    = (int*)alloc((size_t)E * 4);
    float* onorm   = (float*)alloc((size_t)N_NODES * 4);
    float* innorm  = (float*)alloc((size_t)N_NODES * 4);
    _Float16* W1T  = (_Float16*)alloc((size_t)IN_SIZE * HID * 2);
    _Float16* W2T  = (_Float16*)alloc((size_t)HID * OUT * 2);
    _Float16* X1   = (_Float16*)alloc((size_t)N_NODES * HID * 2);
    _Float16* X2   = (_Float16*)alloc((size_t)N_NODES * OUT * 2);
    (void)ws_size; (void)n_in; (void)out_size;

    const int EPB = (E + NB - 1) / NB;
    const int WTB = (IN_SIZE * HID + HID * OUT + 255) / 256;
    const int ZB  = (N_NODES + 255) / 256;

    // CSR build — global atomics only for out-degree (fire-and-forget, exact integer counts)
    k_zero<<<ZB, 256, 0, stream>>>(outdeg);
    k_hist_wt<<<NB + WTB, 256, 0, stream>>>(srcp, dstp, hist, outdeg, E, EPB, W1, W1T, W2, W2T);
    k_scanA<<<NBUCK, 256, 0, stream>>>(hist, bsum);
    k_scanB<<<1, 512, 0, stream>>>(bsum, bb);
    k_cscatter<<<NB, 256, 0, stream>>>(srcp, dstp, hist, bb, tmp, E, EPB);
    k_fine<<<NBUCK, 256, 0, stream>>>(tmp, bb, outdeg, rp, esrc, innorm, onorm);

    // dense + aggregation pipeline (gemm2 fused into agg1 epilogue)
    k_gemm1_mfma<<<((N_NODES + 63) / 64) * 2, 256, 0, stream>>>(feat, W1T, onorm, X1);
    k_agg1_fused<<<(N_NODES + 15) / 16, 256, 0, stream>>>(X1, rp, esrc, innorm, onorm, b1, W2T, X2);
    k_agg2<<<(N_NODES + 31) / 32, 256, 0, stream>>>(X2, rp, esrc, innorm, b2, out);
}